// Round 1
// baseline (696.155 us; speedup 1.0000x reference)
//
#include <hip/hip_runtime.h>
#include <math.h>

// Problem constants (fixed by the reference file).
#define D_FEAT      128
#define NUM_SEG     16384
#define SEG_PER_BLK 4      // 4 waves per block, one segment per wave

// Phase 1: one pass over sorted segment_ids -> offs[g] = first row with id >= g,
// offs[NUM_SEG] = n. Replaces 16384 x 2 binary searches with one coalesced
// stream over the 4/8 MiB id array. (Proven; unchanged.)
__global__ __launch_bounds__(256) void seg_bounds_kernel(
    const int* __restrict__ seg32, int* __restrict__ offs, int n)
{
    const int i = blockIdx.x * 256 + threadIdx.x;
    if (i >= n) return;
    // Runtime dtype detection (ids sorted, 0 <= id < 16384): if the int32
    // view's last element is 0 it's the high word of an int64 array.
    const bool wide = (seg32[n - 1] == 0);
    int cur, prev;
    if (wide) {
        const long long* s = (const long long*)seg32;
        cur  = (int)s[i];
        prev = (i == 0) ? -1 : (int)s[i - 1];
    } else {
        cur  = seg32[i];
        prev = (i == 0) ? -1 : seg32[i - 1];
    }
    for (int g = prev + 1; g <= cur; ++g) offs[g] = i;   // writes only at boundaries
    if (i == n - 1) {
        for (int g = cur + 1; g <= NUM_SEG; ++g) offs[g] = n;
    }
}

// Phase 2: ONE WAVE PER SEGMENT. Lane l owns columns {2l, 2l+1} (float2), so
// each row is exactly one fully-coalesced 512 B global_load_dwordx2 per wave.
// No LDS, no __syncthreads, no cross-lane combine. Main loop keeps 16
// independent loads (128 B/lane, 8 KiB/wave) in flight -> bandwidth-bound,
// not latency-bound. 4 independent waves (segments) per 256-thread block.
__global__ __launch_bounds__(256) void seg_pool_kernel(
    const float* __restrict__ x,
    const int*   __restrict__ offs,
    float*       __restrict__ out)
{
    const int wave = threadIdx.x >> 6;   // 0..3: which segment of this block
    const int lane = threadIdx.x & 63;   // lane owns float2 column pair
    const int g = blockIdx.x * SEG_PER_BLK + wave;

    const int start = offs[g];
    const int end   = offs[g + 1];

    const float* xc = x + (lane << 1);   // 2 floats per lane

    float2 mx = make_float2(-INFINITY, -INFINITY);
    float2 mn = make_float2( INFINITY,  INFINITY);
    float2 sm = make_float2(0.f, 0.f);
    float2 sq = make_float2(0.f, 0.f);

#define LDR(k) const float2 v##k = *(const float2*)(xc + (size_t)(r + (k)) * D_FEAT)
#define ACC(v) do {                                                   \
        mx.x = fmaxf(mx.x, (v).x);  mx.y = fmaxf(mx.y, (v).y);        \
        mn.x = fminf(mn.x, (v).x);  mn.y = fminf(mn.y, (v).y);        \
        sm.x += (v).x;              sm.y += (v).y;                    \
        sq.x = fmaf((v).x, (v).x, sq.x);                              \
        sq.y = fmaf((v).y, (v).y, sq.y);                              \
    } while (0)

    int r = start;
    // Main: 16 independent dwordx2 loads issued before any use.
    for (; r + 15 < end; r += 16) {
        LDR(0);  LDR(1);  LDR(2);  LDR(3);
        LDR(4);  LDR(5);  LDR(6);  LDR(7);
        LDR(8);  LDR(9);  LDR(10); LDR(11);
        LDR(12); LDR(13); LDR(14); LDR(15);
        ACC(v0);  ACC(v1);  ACC(v2);  ACC(v3);
        ACC(v4);  ACC(v5);  ACC(v6);  ACC(v7);
        ACC(v8);  ACC(v9);  ACC(v10); ACC(v11);
        ACC(v12); ACC(v13); ACC(v14); ACC(v15);
    }
    // Mid tail: 4 in flight.
    for (; r + 3 < end; r += 4) {
        LDR(0); LDR(1); LDR(2); LDR(3);
        ACC(v0); ACC(v1); ACC(v2); ACC(v3);
    }
    // Last <=3 rows.
    for (; r < end; ++r) {
        LDR(0);
        ACC(v0);
    }
#undef LDR
#undef ACC

    const float fc    = (float)(end - start);
    const float inv_c = 1.0f / fc;
    const float inv_m = 1.0f / (fc - 1.0f);

    float2 mean = make_float2(sm.x * inv_c, sm.y * inv_c);
    // Unbiased variance, same formula as the reference:
    // var = (sumsq - cnt*mean^2) / (cnt - 1), clamped at 0.
    float2 stdv;
    stdv.x = sqrtf(fmaxf((sq.x - fc * mean.x * mean.x) * inv_m, 0.0f));
    stdv.y = sqrtf(fmaxf((sq.y - fc * mean.y * mean.y) * inv_m, 0.0f));

    // All 64 lanes store: 4 stats x 512 B contiguous per wave.
    float* base = out + (size_t)g * (4 * D_FEAT) + (lane << 1);
    *(float2*)(base + 0 * D_FEAT) = mx;
    *(float2*)(base + 1 * D_FEAT) = mn;
    *(float2*)(base + 2 * D_FEAT) = mean;
    *(float2*)(base + 3 * D_FEAT) = stdv;
}

extern "C" void kernel_launch(void* const* d_in, const int* in_sizes, int n_in,
                              void* d_out, int out_size, void* d_ws, size_t ws_size,
                              hipStream_t stream) {
    const float* x   = (const float*)d_in[0];
    const int*   seg = (const int*)d_in[1];
    float*       out = (float*)d_out;
    int*         offs = (int*)d_ws;        // NUM_SEG+1 ints of scratch
    const int n = in_sizes[0] / D_FEAT;    // 1048576 rows

    seg_bounds_kernel<<<(n + 255) / 256, 256, 0, stream>>>(seg, offs, n);
    seg_pool_kernel<<<NUM_SEG / SEG_PER_BLK, 256, 0, stream>>>(x, offs, out);
}